// Round 10
// baseline (49.912 us; speedup 1.0000x reference)
//
#include <hip/hip_runtime.h>
#include <hip/hip_bf16.h>

// Causal conv1d as bf16 MFMA GEMM — 128x128 tile, 3 blocks/CU, 1 barrier/step.
// out[b,h,t] = sum_{c,k} x[b,c,t+k-3] * W[h, c*4+k] + bias[h]
// B=8, C=256, T=4096, H=512, K=4.

#define Bb 8
#define Cc 256
#define Tt 4096
#define Hh 512
#define Kk 4

typedef __attribute__((ext_vector_type(8))) short bf16x8;
typedef __attribute__((ext_vector_type(4))) float f32x4;

#define WS_XT_OFF   0
#define WS_WT_OFF   16777216
#define WS_ZERO_OFF 17825792
#define WS_NEEDED   17826816ULL

__device__ __forceinline__ void gload16(const void* g, void* l) {
    __builtin_amdgcn_global_load_lds(
        (const __attribute__((address_space(1))) void*)g,
        (__attribute__((address_space(3))) void*)l, 16, 0, 0);
}

// ---------- merged prep: xT transpose (blocks 0..2047) + Wt[k][h][c] pack ----------
__global__ __launch_bounds__(256) void prep_kernel(const float* __restrict__ x,
                                                   const float* __restrict__ W,
                                                   __hip_bfloat16* __restrict__ xT,
                                                   __hip_bfloat16* __restrict__ Wt,
                                                   float* __restrict__ zeros) {
    __shared__ __hip_bfloat16 tile[64][72];
    const int bid = blockIdx.x;
    if (bid < 2048) {
        const int t0 = (bid & 63) * 64, c0 = ((bid >> 6) & 3) * 64, b = bid >> 8;
        const int lt = threadIdx.x & 63, lw = threadIdx.x >> 6;
#pragma unroll
        for (int i = 0; i < 16; ++i) {
            int cc = lw + i * 4;
            tile[cc][lt] = __float2bfloat16(x[((size_t)(b * Cc + c0 + cc)) * Tt + t0 + lt]);
        }
        __syncthreads();
#pragma unroll
        for (int i = 0; i < 2; ++i) {
            int tt = (threadIdx.x >> 3) + i * 32;
            int c8 = threadIdx.x & 7;
            short tmp[8];
#pragma unroll
            for (int j = 0; j < 8; ++j) {
                __hip_bfloat16 v = tile[c8 * 8 + j][tt];
                tmp[j] = *reinterpret_cast<short*>(&v);
            }
            *reinterpret_cast<bf16x8*>(&xT[((size_t)(b * Tt + t0 + tt)) * Cc + c0 + c8 * 8]) =
                *reinterpret_cast<bf16x8*>(tmp);
        }
    } else {
        int n = (bid - 2048) * 256 + threadIdx.x;     // [0, 4*512*256)
        int c = n & 255;
        int h = (n >> 8) & 511;
        int k = n >> 17;
        Wt[n] = __float2bfloat16(W[h * (Cc * Kk) + c * Kk + k]);
        if (bid == 2048) zeros[threadIdx.x] = 0.f;    // 1 KB zero page
    }
}

// ---------- main: BM=128h x BN=128t, 4 waves (2x2 -> 64x64/wave), 16x16x32 ----------
// 16 K-steps of GEMM-K 64 = 2 conv-k x 32 ch (kpair = s&1, cblk = s>>1).
// LDS: A 2 bufs x [2kk][128 rows][4 slots x 16B] = 2x16384;
//      B 2 bufs x [144 rows][4 slots x 16B] = 2x9216.  Total 51200 -> 3 blocks/CU.
// Swizzle (r6-validated): slot_phys = slot_log ^ ((row>>1)&3), folded into global src.
#define A_BUF    16384
#define B_BUF    9216
#define B_BASE   32768
#define LDS_TOTAL 51200

#define BAR __builtin_amdgcn_s_barrier()
#define LGKM0 do { asm volatile("s_waitcnt lgkmcnt(0)" ::: "memory"); \
                   __builtin_amdgcn_sched_barrier(0); } while (0)

__global__ __launch_bounds__(256, 3) void conv_mfma_kernel(
    const __hip_bfloat16* __restrict__ xT,
    const __hip_bfloat16* __restrict__ Wt,
    const float* __restrict__ bias,
    const float* __restrict__ zeros,
    float* __restrict__ out)
{
    __shared__ __align__(1024) char smem[LDS_TOTAL];
    const int tid = threadIdx.x, lane = tid & 63, wave = tid >> 6;
    const int wr = wave >> 1, wc = wave & 1;          // 2(M h) x 2(N t)
    const int l15 = lane & 15, lg = lane >> 4;

    // XCD-bijective swizzle: 1024 blocks = 8 XCD x 128; batch <-> XCD.
    // Inner order: 4 h-tiles share each t-window (L2-hot xT slice reused 4x).
    const int flat = blockIdx.x + 32 * blockIdx.y + 128 * blockIdx.z;
    const int nf   = (flat & 7) * 128 + (flat >> 3);
    const int h0 = (nf & 3) * 128;
    const int t0 = ((nf >> 2) & 31) * 128;
    const int b  = nf >> 7;

    const char* Wt_c = (const char*)Wt;
    const char* xT_c = (const char*)xT;
    const char* zz   = (const char*)zeros;

    // ---- A staging descriptors (linear LDS dst; swizzle folded into global src) ----
    const char* asrc[4]; int adst_[4];
#pragma unroll
    for (int i = 0; i < 4; ++i) {
        int s = tid + i * 256;                        // 0..1023
        int kk = s >> 9, row = (s >> 2) & 127, sl = s & 3;
        int colch = (sl ^ ((row >> 1) & 3)) * 8;
        asrc[i] = Wt_c + (((size_t)(kk * Hh + h0 + row)) * Cc + colch) * 2;
        adst_[i] = s * 16;
    }
    // ---- B staging descriptors (slots 0..511 all threads, 512..575 wave0) ----
    const char* bsrc[3]; int bdst_[3]; int bstep[3];
#pragma unroll
    for (int i = 0; i < 3; ++i) {
        int s = (i < 2) ? tid + i * 256 : 512 + lane; // rows 0..143
        int row = s >> 2, sl = s & 3;
        int colch = (sl ^ ((row >> 1) & 3)) * 8;
        int tg = t0 - 3 + row;
        bool valid = (row <= 130) && (tg >= 0);
        bsrc[i]  = valid ? xT_c + (((size_t)b * Tt + tg) * Cc + colch) * 2
                         : zz + (s & 15) * 16;
        bstep[i] = valid ? 64 : 0;                    // +64B per c-block; zeros stay put
        bdst_[i] = s * 16;
    }

    // ---- fragment read offsets (r6-validated swizzle) ----
    const int aoffb = (wr * 64 + l15) * 64 + ((lg ^ ((l15 >> 1) & 3)) << 4);
    int btab[4];
#pragma unroll
    for (int k = 0; k < 4; ++k)
        btab[k] = (wc * 64 + l15 + k) * 64 + ((lg ^ (((l15 + k) >> 1) & 3)) << 4);

    f32x4 acc[4][4] = {};

    // ---- prologue: stage A(0), B(0); drain; barrier ----
#pragma unroll
    for (int i = 0; i < 4; ++i) gload16(asrc[i], smem + adst_[i]);
#pragma unroll
    for (int i = 0; i < 2; ++i) gload16(bsrc[i], smem + B_BASE + bdst_[i]);
    if (wave == 0) gload16(bsrc[2], smem + B_BASE + bdst_[2]);
    asm volatile("s_waitcnt vmcnt(0)" ::: "memory");
    BAR;

    // ---- main loop: 16 steps, 1 barrier each ----
#pragma unroll
    for (int s = 0; s < 16; ++s) {
        const int p  = s >> 1;
        const int kb = 2 * (s & 1);
        const char* Ab = smem + (s & 1) * A_BUF;
        const char* Bbf = smem + B_BASE + (p & 1) * B_BUF;

        // stage A(s+1) first (drained by this step's vmcnt)
        if (s < 15) {
            const long aadv = (long)((s + 1) & 1) * 524288 + (long)((s + 1) >> 1) * 64;
            char* An = smem + ((s + 1) & 1) * A_BUF;
#pragma unroll
            for (int i = 0; i < 4; ++i) gload16(asrc[i] + aadv, An + adst_[i]);
        }
        // stage B(p+1) on even steps (stays in flight across the barrier)
        if (((s & 1) == 0) && (p < 7)) {
            char* Bn = smem + B_BASE + ((p + 1) & 1) * B_BUF;
#pragma unroll
            for (int i = 0; i < 2; ++i) gload16(bsrc[i] + (p + 1) * bstep[i], Bn + bdst_[i]);
            if (wave == 0) gload16(bsrc[2] + (p + 1) * bstep[2], Bn + bdst_[2]);
        }

        bf16x8 a_[4], b_[4];
        // -- phase 0: conv-k = kb, kk-half 0 --
#pragma unroll
        for (int fm = 0; fm < 4; ++fm) a_[fm] = *(const bf16x8*)(Ab + aoffb + fm * 1024);
#pragma unroll
        for (int ft = 0; ft < 4; ++ft) b_[ft] = *(const bf16x8*)(Bbf + btab[kb] + ft * 1024);
        LGKM0;
        __builtin_amdgcn_s_setprio(1);
#pragma unroll
        for (int fm = 0; fm < 4; ++fm)
#pragma unroll
            for (int ft = 0; ft < 4; ++ft)
                acc[fm][ft] = __builtin_amdgcn_mfma_f32_16x16x32_bf16(a_[fm], b_[ft], acc[fm][ft], 0, 0, 0);
        __builtin_amdgcn_s_setprio(0);
        // -- phase 1: conv-k = kb+1, kk-half 1 --
#pragma unroll
        for (int fm = 0; fm < 4; ++fm) a_[fm] = *(const bf16x8*)(Ab + 8192 + aoffb + fm * 1024);
#pragma unroll
        for (int ft = 0; ft < 4; ++ft) b_[ft] = *(const bf16x8*)(Bbf + btab[kb + 1] + ft * 1024);
        LGKM0;
        __builtin_amdgcn_s_setprio(1);
#pragma unroll
        for (int fm = 0; fm < 4; ++fm)
#pragma unroll
            for (int ft = 0; ft < 4; ++ft)
                acc[fm][ft] = __builtin_amdgcn_mfma_f32_16x16x32_bf16(a_[fm], b_[ft], acc[fm][ft], 0, 0, 0);
        __builtin_amdgcn_s_setprio(0);

        // counted wait: drain A(s+1); B(p+1) (issued after A) stays in flight
        if (s < 15) {
            if (((s & 1) == 0) && (p < 7)) asm volatile("s_waitcnt vmcnt(3)" ::: "memory");
            else                           asm volatile("s_waitcnt vmcnt(0)" ::: "memory");
            BAR;
        }
    }

    // ---- epilogue: D col=l15 -> t, row=lg*4+q -> h (validated mapping) ----
#pragma unroll
    for (int fm = 0; fm < 4; ++fm) {
        int hb = h0 + wr * 64 + fm * 16 + lg * 4;
        float4 bs = *(const float4*)&bias[hb];
        const float* bsp = (const float*)&bs;
#pragma unroll
        for (int q = 0; q < 4; ++q)
#pragma unroll
            for (int ft = 0; ft < 4; ++ft) {
                int t = t0 + wc * 64 + ft * 16 + l15;
                out[((size_t)(b * Hh + hb + q)) * Tt + t] = acc[fm][ft][q] + bsp[q];
            }
    }
}

// ---------------- fallback (ws too small): fp32 kernel ----------------
#define TT 256
#define HT 8
#define CT 4
__global__ __launch_bounds__(256) void conv1d_f32_kernel(
    const float* __restrict__ x, const float* __restrict__ W,
    const float* __restrict__ bias, float* __restrict__ out)
{
    const int tid = threadIdx.x;
    const int t0 = blockIdx.x * TT;
    const int h0 = blockIdx.y * HT;
    const int b  = blockIdx.z;
    __shared__ float xs[CT][TT + Kk];
    float acc[HT];
#pragma unroll
    for (int h = 0; h < HT; ++h) acc[h] = 0.f;
    const float* xb = x + (size_t)b * Cc * Tt;
    for (int c0 = 0; c0 < Cc; c0 += CT) {
        __syncthreads();
#pragma unroll
        for (int cc = 0; cc < CT; ++cc)
            for (int j = tid; j < TT + Kk - 1; j += 256) {
                int idx = t0 - (Kk - 1) + j;
                xs[cc][j] = (idx >= 0) ? xb[(size_t)(c0 + cc) * Tt + idx] : 0.f;
            }
        __syncthreads();
#pragma unroll
        for (int cc = 0; cc < CT; ++cc) {
            float xv[Kk];
#pragma unroll
            for (int k = 0; k < Kk; ++k) xv[k] = xs[cc][tid + k];
#pragma unroll
            for (int h = 0; h < HT; ++h) {
                const float* wp = W + (size_t)(h0 + h) * (Cc * Kk) + (size_t)(c0 + cc) * Kk;
#pragma unroll
                for (int k = 0; k < Kk; ++k) acc[h] += wp[k] * xv[k];
            }
        }
    }
#pragma unroll
    for (int h = 0; h < HT; ++h)
        out[((size_t)b * Hh + (h0 + h)) * Tt + t0 + tid] = acc[h] + bias[h0 + h];
}

extern "C" void kernel_launch(void* const* d_in, const int* in_sizes, int n_in,
                              void* d_out, int out_size, void* d_ws, size_t ws_size,
                              hipStream_t stream) {
    const float* x    = (const float*)d_in[0];
    const float* W    = (const float*)d_in[1];
    const float* bias = (const float*)d_in[2];
    float* out        = (float*)d_out;

    if (ws_size >= WS_NEEDED) {
        __hip_bfloat16* xT = (__hip_bfloat16*)((char*)d_ws + WS_XT_OFF);
        __hip_bfloat16* Wt = (__hip_bfloat16*)((char*)d_ws + WS_WT_OFF);
        float* zeros       = (float*)((char*)d_ws + WS_ZERO_OFF);

        prep_kernel<<<dim3(4096), dim3(256), 0, stream>>>(x, W, xT, Wt, zeros);
        conv_mfma_kernel<<<dim3(32, 4, 8), dim3(256), 0, stream>>>(xT, Wt, bias, zeros, out);
    } else {
        conv1d_f32_kernel<<<dim3(Tt / TT, Hh / HT, Bb), dim3(256), 0, stream>>>(x, W, bias, out);
    }
}